// Round 1
// baseline (42.144 us; speedup 1.0000x reference)
//
#include <hip/hip_runtime.h>
#include <math.h>

namespace {

constexpr int N = 512;
constexpr int D = 512;
constexpr float MARGIN = 1.0f;

// Kernel 1: per-row sum of squares; block 0 also zeroes the accumulators.
__global__ void sq_kernel(const float* __restrict__ x, float* __restrict__ sq,
                          float* __restrict__ acc) {
  const int r = blockIdx.x;
  const int lane = threadIdx.x;  // 64 threads = 1 wave
  const float4* xr = reinterpret_cast<const float4*>(x + (size_t)r * D);
  float4 a = xr[lane];
  float4 b = xr[lane + 64];
  float s = a.x * a.x + a.y * a.y + a.z * a.z + a.w * a.w +
            b.x * b.x + b.y * b.y + b.z * b.z + b.w * b.w;
#pragma unroll
  for (int o = 32; o; o >>= 1) s += __shfl_xor(s, o, 64);
  if (lane == 0) sq[r] = s;
  if (r == 0 && lane == 0) {
    acc[0] = 0.0f;  // loss numerator
    acc[1] = 0.0f;  // num_pos
  }
}

// Kernel 2: pd = clamp(sq_i + sq_j - 2*x@x^T, 0), zero diagonal.
// 32x32 output tile per block, 2x2 per thread, K staged in LDS (pad +1).
__global__ void pd_kernel(const float* __restrict__ x, const float* __restrict__ sq,
                          float* __restrict__ pd) {
  __shared__ float As[32][33];
  __shared__ float Bs[32][33];
  const int tx = threadIdx.x & 15;
  const int ty = threadIdx.x >> 4;
  const int bi = blockIdx.y * 32;
  const int bj = blockIdx.x * 32;
  const int lr = threadIdx.x >> 3;        // 0..31 (row of staging load)
  const int lc = (threadIdx.x & 7) << 2;  // 0,4,..,28 (col, float4)
  float a00 = 0.f, a01 = 0.f, a10 = 0.f, a11 = 0.f;
  for (int k0 = 0; k0 < D; k0 += 32) {
    float4 va = *reinterpret_cast<const float4*>(&x[(size_t)(bi + lr) * D + k0 + lc]);
    float4 vb = *reinterpret_cast<const float4*>(&x[(size_t)(bj + lr) * D + k0 + lc]);
    As[lr][lc] = va.x; As[lr][lc + 1] = va.y; As[lr][lc + 2] = va.z; As[lr][lc + 3] = va.w;
    Bs[lr][lc] = vb.x; Bs[lr][lc + 1] = vb.y; Bs[lr][lc + 2] = vb.z; Bs[lr][lc + 3] = vb.w;
    __syncthreads();
#pragma unroll
    for (int kk = 0; kk < 32; ++kk) {
      float A0 = As[ty * 2 + 0][kk], A1 = As[ty * 2 + 1][kk];
      float B0 = Bs[tx * 2 + 0][kk], B1 = Bs[tx * 2 + 1][kk];
      a00 = fmaf(A0, B0, a00);
      a01 = fmaf(A0, B1, a01);
      a10 = fmaf(A1, B0, a10);
      a11 = fmaf(A1, B1, a11);
    }
    __syncthreads();
  }
  const int i0 = bi + ty * 2, j0 = bj + tx * 2;
  float accv[2][2] = {{a00, a01}, {a10, a11}};
#pragma unroll
  for (int ri = 0; ri < 2; ++ri) {
#pragma unroll
    for (int cj = 0; cj < 2; ++cj) {
      const int i = i0 + ri, j = j0 + cj;
      float v = sq[i] + sq[j] - 2.0f * accv[ri][cj];
      v = fmaxf(v, 0.0f);
      if (i == j) v = 0.0f;
      pd[(size_t)i * N + j] = v;
    }
  }
}

// Kernel 3: per anchor row r — neg_in = max over negatives (0 if none, since
// rowmin is always 0), then for each positive i: semi-hard = min over negatives
// with pd[r,k] > pd[r,i], fallback neg_in. Accumulate hinge terms + pair count.
__global__ void row_kernel(const float* __restrict__ pd, const int* __restrict__ labels,
                           float* __restrict__ acc) {
  const int r = blockIdx.x;
  __shared__ float row[N];
  __shared__ int lab[N];
  __shared__ short pos[N];
  __shared__ int poscount;
  __shared__ float s_red[4];
  __shared__ float s_negin;
  __shared__ float s_loss[4];
  if (threadIdx.x == 0) poscount = 0;
  __syncthreads();
  const int lr = labels[r];
  float mx = 0.0f;  // neg_in fallback is rowmin == 0 (diag is 0, pd >= 0)
  for (int k = threadIdx.x; k < N; k += 256) {
    float v = pd[(size_t)r * N + k];
    int lk = labels[k];
    row[k] = v;
    lab[k] = lk;
    if (lk != lr) {
      mx = fmaxf(mx, v);
    } else if (k != r) {
      int idx = atomicAdd(&poscount, 1);
      pos[idx] = (short)k;
    }
  }
#pragma unroll
  for (int o = 32; o; o >>= 1) mx = fmaxf(mx, __shfl_xor(mx, o, 64));
  const int wid = threadIdx.x >> 6;
  const int lane = threadIdx.x & 63;
  if (lane == 0) s_red[wid] = mx;
  __syncthreads();
  if (threadIdx.x == 0) {
    s_negin = fmaxf(fmaxf(s_red[0], s_red[1]), fmaxf(s_red[2], s_red[3]));
  }
  __syncthreads();
  const float negin = s_negin;
  const int npos = poscount;
  float wsum = 0.0f;
  for (int p = wid; p < npos; p += 4) {  // one wave per positive
    const int i = pos[p];
    const float di = row[i];
    float mn = 3.4e38f;
#pragma unroll
    for (int kb = 0; kb < N; kb += 64) {
      const int k = kb + lane;
      const float v = row[k];
      if (lab[k] != lr && v > di) mn = fminf(mn, v);
    }
#pragma unroll
    for (int o = 32; o; o >>= 1) mn = fminf(mn, __shfl_xor(mn, o, 64));
    const float semi = (mn < 1.0e30f) ? mn : negin;  // pd <= 4 for unit vectors
    const float term = fmaxf(MARGIN + di - semi, 0.0f);
    if (lane == 0) wsum += term;
  }
  if (lane == 0) s_loss[wid] = wsum;
  __syncthreads();
  if (threadIdx.x == 0) {
    const float t = s_loss[0] + s_loss[1] + s_loss[2] + s_loss[3];
    atomicAdd(&acc[0], t);
    atomicAdd(&acc[1], (float)npos);
  }
}

__global__ void finalize_kernel(const float* __restrict__ acc, float* __restrict__ out) {
  float np = acc[1];
  if (np == 0.0f) np = 1e-5f;
  out[0] = acc[0] / np;
}

}  // namespace

extern "C" void kernel_launch(void* const* d_in, const int* in_sizes, int n_in,
                              void* d_out, int out_size, void* d_ws, size_t ws_size,
                              hipStream_t stream) {
  const float* x = (const float*)d_in[0];
  const int* labels = (const int*)d_in[1];
  float* out = (float*)d_out;

  float* pd = (float*)d_ws;                 // N*N f32 = 1 MiB
  float* sq = pd + (size_t)N * N;           // N f32
  float* acc = sq + N;                      // 2 f32: {loss numerator, num_pos}

  sq_kernel<<<N, 64, 0, stream>>>(x, sq, acc);
  pd_kernel<<<dim3(N / 32, N / 32), 256, 0, stream>>>(x, sq, pd);
  row_kernel<<<N, 256, 0, stream>>>(pd, labels, acc);
  finalize_kernel<<<1, 1, 0, stream>>>(acc, out);
}

// Round 2
// 41.408 us; speedup vs baseline: 1.0178x; 1.0178x over previous
//
#include <hip/hip_runtime.h>
#include <math.h>

namespace {

constexpr int N = 512;
constexpr int D = 512;
constexpr float MARGIN = 1.0f;

// Kernel 1: pd = clamp(sq_i + sq_j - 2*x@x^T, 0), zero diagonal.
// 32x32 output tile per block, 2x2 per thread. Row sum-of-squares (sq) is
// computed inline from the staged tiles (no separate sq kernel). Block (0,0)
// zeroes the accumulators {loss, npos, ticket}.
// LDS tiles stored TRANSPOSED (As[k][i]) so inner-loop fragment reads are
// contiguous float2 (ds_read_b64) instead of 2x strided b32.
__global__ __launch_bounds__(256) void pd_kernel(const float* __restrict__ x,
                                                 float* __restrict__ pd,
                                                 float* __restrict__ acc) {
  __shared__ float As[32][34];  // [k within tile][row i], stride 34 keeps float2 aligned + conflict-free
  __shared__ float Bs[32][34];
  __shared__ float sA[32];      // per-row sumsq for this block's A rows
  __shared__ float sB[32];
  const int tx = threadIdx.x & 15;
  const int ty = threadIdx.x >> 4;
  const int bi = blockIdx.y * 32;
  const int bj = blockIdx.x * 32;
  const int lr = threadIdx.x >> 3;        // 0..31 staging row
  const int lc = (threadIdx.x & 7) << 2;  // 0,4,..,28 staging col (float4)

  if (blockIdx.x == 0 && blockIdx.y == 0 && threadIdx.x < 3) {
    acc[threadIdx.x] = 0.0f;  // loss numerator, num_pos, ticket
  }

  float ssa = 0.0f, ssb = 0.0f;
  float a00 = 0.f, a01 = 0.f, a10 = 0.f, a11 = 0.f;
  for (int k0 = 0; k0 < D; k0 += 32) {
    float4 va = *reinterpret_cast<const float4*>(&x[(size_t)(bi + lr) * D + k0 + lc]);
    float4 vb = *reinterpret_cast<const float4*>(&x[(size_t)(bj + lr) * D + k0 + lc]);
    ssa += va.x * va.x + va.y * va.y + va.z * va.z + va.w * va.w;
    ssb += vb.x * vb.x + vb.y * vb.y + vb.z * vb.z + vb.w * vb.w;
    As[lc + 0][lr] = va.x; As[lc + 1][lr] = va.y; As[lc + 2][lr] = va.z; As[lc + 3][lr] = va.w;
    Bs[lc + 0][lr] = vb.x; Bs[lc + 1][lr] = vb.y; Bs[lc + 2][lr] = vb.z; Bs[lc + 3][lr] = vb.w;
    __syncthreads();
#pragma unroll
    for (int kk = 0; kk < 32; ++kk) {
      float2 A = *reinterpret_cast<const float2*>(&As[kk][ty * 2]);
      float2 B = *reinterpret_cast<const float2*>(&Bs[kk][tx * 2]);
      a00 = fmaf(A.x, B.x, a00);
      a01 = fmaf(A.x, B.y, a01);
      a10 = fmaf(A.y, B.x, a10);
      a11 = fmaf(A.y, B.y, a11);
    }
    __syncthreads();
  }
  // Reduce sumsq partials over the 8 threads that loaded each row (they are
  // 8 consecutive lanes within one wave).
#pragma unroll
  for (int o = 1; o < 8; o <<= 1) {
    ssa += __shfl_xor(ssa, o, 64);
    ssb += __shfl_xor(ssb, o, 64);
  }
  if ((threadIdx.x & 7) == 0) {
    sA[lr] = ssa;
    sB[lr] = ssb;
  }
  __syncthreads();

  const int i0 = bi + ty * 2, j0 = bj + tx * 2;
  float accv[2][2] = {{a00, a01}, {a10, a11}};
#pragma unroll
  for (int ri = 0; ri < 2; ++ri) {
    const int i = i0 + ri;
    float2 o2;
    float v0 = sA[ty * 2 + ri] + sB[tx * 2 + 0] - 2.0f * accv[ri][0];
    float v1 = sA[ty * 2 + ri] + sB[tx * 2 + 1] - 2.0f * accv[ri][1];
    v0 = fmaxf(v0, 0.0f);
    v1 = fmaxf(v1, 0.0f);
    if (i == j0 + 0) v0 = 0.0f;
    if (i == j0 + 1) v1 = 0.0f;
    o2.x = v0; o2.y = v1;
    *reinterpret_cast<float2*>(&pd[(size_t)i * N + j0]) = o2;
  }
}

// Kernel 2: per anchor row r — neg_in = max over negatives (rowmin is always 0
// since diag=0 and pd>=0); for each positive i: semi-hard = min over negatives
// with pd[r,k] > pd[r,i], fallback neg_in. Accumulate hinge terms + pair count
// via device atomics; the LAST block to finish computes out = loss / num_pos.
__global__ __launch_bounds__(256) void row_kernel(const float* __restrict__ pd,
                                                  const int* __restrict__ labels,
                                                  float* __restrict__ acc,
                                                  float* __restrict__ out) {
  const int r = blockIdx.x;
  __shared__ float row[N];
  __shared__ int lab[N];
  __shared__ short pos[N];
  __shared__ int poscount;
  __shared__ float s_red[4];
  __shared__ float s_negin;
  __shared__ float s_loss[4];
  if (threadIdx.x == 0) poscount = 0;
  __syncthreads();
  const int lr = labels[r];
  float mx = 0.0f;  // neg_in fallback; rowmin == 0 always
  {
    const int k2 = threadIdx.x;  // 0..255, two elements each
    float2 v2 = reinterpret_cast<const float2*>(pd + (size_t)r * N)[k2];
    int2 l2 = reinterpret_cast<const int2*>(labels)[k2];
    const int ka = 2 * k2, kb = 2 * k2 + 1;
    row[ka] = v2.x; row[kb] = v2.y;
    lab[ka] = l2.x; lab[kb] = l2.y;
    if (l2.x != lr) mx = fmaxf(mx, v2.x);
    else if (ka != r) pos[atomicAdd(&poscount, 1)] = (short)ka;
    if (l2.y != lr) mx = fmaxf(mx, v2.y);
    else if (kb != r) pos[atomicAdd(&poscount, 1)] = (short)kb;
  }
#pragma unroll
  for (int o = 32; o; o >>= 1) mx = fmaxf(mx, __shfl_xor(mx, o, 64));
  const int wid = threadIdx.x >> 6;
  const int lane = threadIdx.x & 63;
  if (lane == 0) s_red[wid] = mx;
  __syncthreads();
  if (threadIdx.x == 0) {
    s_negin = fmaxf(fmaxf(s_red[0], s_red[1]), fmaxf(s_red[2], s_red[3]));
  }
  __syncthreads();
  const float negin = s_negin;
  const int npos = poscount;
  float wsum = 0.0f;
  for (int p = wid; p < npos; p += 4) {  // one wave per positive
    const int i = pos[p];
    const float di = row[i];
    float mn = 3.4e38f;
#pragma unroll
    for (int kb2 = 0; kb2 < N; kb2 += 64) {
      const int k = kb2 + lane;
      const float v = row[k];
      if (lab[k] != lr && v > di) mn = fminf(mn, v);
    }
#pragma unroll
    for (int o = 32; o; o >>= 1) mn = fminf(mn, __shfl_xor(mn, o, 64));
    const float semi = (mn < 1.0e30f) ? mn : negin;  // pd <= 4 for unit vectors
    const float term = fmaxf(MARGIN + di - semi, 0.0f);
    if (lane == 0) wsum += term;
  }
  if (lane == 0) s_loss[wid] = wsum;
  __syncthreads();
  if (threadIdx.x == 0) {
    const float t = s_loss[0] + s_loss[1] + s_loss[2] + s_loss[3];
    atomicAdd(&acc[0], t);
    atomicAdd(&acc[1], (float)npos);
    __threadfence();
    unsigned old = atomicAdd(reinterpret_cast<unsigned*>(&acc[2]), 1u);
    if (old == (unsigned)(gridDim.x - 1)) {
      // Last block: coherent read via atomic RMW, then finalize.
      float ls = atomicAdd(&acc[0], 0.0f);
      float np = atomicAdd(&acc[1], 0.0f);
      if (np == 0.0f) np = 1e-5f;
      out[0] = ls / np;
    }
  }
}

}  // namespace

extern "C" void kernel_launch(void* const* d_in, const int* in_sizes, int n_in,
                              void* d_out, int out_size, void* d_ws, size_t ws_size,
                              hipStream_t stream) {
  const float* x = (const float*)d_in[0];
  const int* labels = (const int*)d_in[1];
  float* out = (float*)d_out;

  float* pd = (float*)d_ws;        // N*N f32 = 1 MiB
  float* acc = pd + (size_t)N * N; // 3 f32: {loss numerator, num_pos, ticket}

  pd_kernel<<<dim3(N / 32, N / 32), 256, 0, stream>>>(x, pd, acc);
  row_kernel<<<N, 256, 0, stream>>>(pd, labels, acc, out);
}